// Round 6
// baseline (544.579 us; speedup 1.0000x reference)
//
#include <hip/hip_runtime.h>

#define NUM_BASIS 67  // GRID_SIZE + K = 64 + 3
#define BLOCK_THREADS 256

typedef float f32x4 __attribute__((ext_vector_type(4)));

// Interior knots: knots[i] = (i-35)/32 for i in [3,67]; clamped to -1 / +1
// outside. Exact in float32 -> comparisons match the reference's indicators.
__device__ __forceinline__ float kv(int i) {
    i = min(max(i, 3), 67);
    return (float)(i - 35) * 0.03125f;
}

// Knot interval m (knots[m] <= x < knots[m+1], m in [3,66]) and the 4 nonzero
// cubic basis values N[0..3] = B_{m-3..m,3}(x). For x outside [-1,1) or NaN:
// m parked far away and N=0 -> all-zero row, matching the reference.
__device__ __forceinline__ void row_basis(float xv, int& m, float N[4]) {
    N[0] = N[1] = N[2] = N[3] = 0.0f;
    m = 1 << 20;
    if (xv >= -1.0f && xv < 1.0f) {
        int cell = (int)floorf((xv + 1.0f) * 32.0f);
        cell = min(max(cell, 0), 63);
        m = cell + 3;
        // Fix-up against exact knot values ((x+1)*32 rounding at boundaries).
        while (m > 3 && xv < kv(m)) --m;
        while (m < 66 && xv >= kv(m + 1)) ++m;

        float left[4], right[4];
        N[0] = 1.0f;
#pragma unroll
        for (int d = 1; d <= 3; ++d) {
            left[d] = xv - kv(m + 1 - d);
            right[d] = kv(m + d) - xv;
            float saved = 0.0f;
#pragma unroll
            for (int r = 0; r < d; ++r) {
                // ~1-ulp fast divide; absmax slack is 5x (3.9e-3 vs 2e-2).
                float temp = __fdividef(N[r], right[r + 1] + left[d - r]);
                N[r] = saved + right[r + 1] * temp;
                saved = left[d - r] * temp;
            }
            N[d] = saved;
        }
    }
}

__device__ __forceinline__ float pick(int d, f32x4 n) {
    float v = 0.0f;
    v = (d == 0) ? n.x : v;
    v = (d == 1) ? n.y : v;
    v = (d == 2) ? n.z : v;
    v = (d == 3) ? n.w : v;
    return v;
}

// Kernel 1: one de Boor triangle per row -> compact (N, m) tables in d_ws.
// 40 MB total; read back immediately by kernel 2 (L2/L3-resident). NOT nt.
__global__ __launch_bounds__(BLOCK_THREADS) void SplineRow_kernel(
        const float* __restrict__ x, f32x4* __restrict__ wsN,
        int* __restrict__ wsM, int B) {
    const int r = blockIdx.x * BLOCK_THREADS + threadIdx.x;
    if (r < B) {
        int m;
        float N[4];
        row_basis(x[r], m, N);
        wsN[r] = (f32x4){N[0], N[1], N[2], N[3]};
        wsM[r] = m;
    }
}

// Kernel 2: fill-shaped thread-level grid-stride sweep over the output.
// At any instant all waves write inside one ~8 MB moving window (near-
// sequential HBM traffic), unlike per-block private regions (34-274 MB
// scatter) which plateaued at ~3.6 TB/s across rounds 1/3/5.
__global__ __launch_bounds__(BLOCK_THREADS) void SplineExpand_kernel(
        const f32x4* __restrict__ wsN, const int* __restrict__ wsM,
        f32x4* __restrict__ out4, int n4, int out_size, int B) {
    const int stride = gridDim.x * BLOCK_THREADS;
    const int t0 = blockIdx.x * BLOCK_THREADS + threadIdx.x;
    for (int i = t0; i < n4; i += stride) {
        const int g = i * 4;                            // < 2^31
        const int r0 = (int)((unsigned)g / NUM_BASIS);  // magic-mul div
        const int c0 = g - r0 * NUM_BASIS;              // [0, 66]
        const int r1 = min(r0 + 1, B - 1);
        // Branchless: always fetch both candidate rows (L1/L2-hit, 17x reuse
        // per row across consecutive lanes) -- no wave-wide divergent path.
        const int m0 = wsM[r0];
        const int m1 = wsM[r1];
        const f32x4 n0 = wsN[r0];
        const f32x4 n1 = wsN[r1];
        f32x4 v;
        int c;
        c = c0 + 0; v.x = (c < NUM_BASIS) ? pick(c - m0 + 3, n0) : pick(c - NUM_BASIS - m1 + 3, n1);
        c = c0 + 1; v.y = (c < NUM_BASIS) ? pick(c - m0 + 3, n0) : pick(c - NUM_BASIS - m1 + 3, n1);
        c = c0 + 2; v.z = (c < NUM_BASIS) ? pick(c - m0 + 3, n0) : pick(c - NUM_BASIS - m1 + 3, n1);
        c = c0 + 3; v.w = (c < NUM_BASIS) ? pick(c - m0 + 3, n0) : pick(c - NUM_BASIS - m1 + 3, n1);
        __builtin_nontemporal_store(v, out4 + i);
    }
    // Scalar tail (not hit for B=2e6: 134e6 % 4 == 0).
    if (t0 == 0) {
        float* out = (float*)out4;
        for (int g = n4 * 4; g < out_size; ++g) {
            const int r0 = (int)((unsigned)g / NUM_BASIS);
            const int c0 = g - r0 * NUM_BASIS;
            out[g] = pick(c0 - wsM[r0] + 3, wsN[r0]);
        }
    }
}

// Fallback (ws too small -- not expected): round-3 single-kernel version.
__global__ __launch_bounds__(BLOCK_THREADS) void SplineFused_kernel(
        const float* __restrict__ x, float* __restrict__ out, int B) {
    __shared__ int s_m[128];
    __shared__ f32x4 s_N[128];
    const int tid = threadIdx.x;
    const int blockRow0 = blockIdx.x * 128;
    if (tid < 128) {
        int m = 1 << 20;
        float N[4] = {0.f, 0.f, 0.f, 0.f};
        const int row = blockRow0 + tid;
        if (row < B) row_basis(x[row], m, N);
        s_m[tid] = m;
        s_N[tid] = (f32x4){N[0], N[1], N[2], N[3]};
    }
    __syncthreads();
    const int rows = min(128, B - blockRow0);
    const int n = rows * NUM_BASIS;
    float* o = out + (size_t)blockRow0 * NUM_BASIS;
    for (int i = tid; i < n; i += BLOCK_THREADS) {
        const int r0 = (int)((unsigned)i / NUM_BASIS);
        const int c0 = i - r0 * NUM_BASIS;
        o[i] = pick(c0 - s_m[r0] + 3, s_N[r0]);
    }
}

extern "C" void kernel_launch(void* const* d_in, const int* in_sizes, int n_in,
                              void* d_out, int out_size, void* d_ws, size_t ws_size,
                              hipStream_t stream) {
    const float* x = (const float*)d_in[0];
    const int B = in_sizes[0];
    const size_t needed = (size_t)B * 16 + (size_t)B * 4;  // N table + m table
    if (ws_size >= needed) {
        f32x4* wsN = (f32x4*)d_ws;
        int* wsM = (int*)((char*)d_ws + (size_t)B * 16);
        const int g1 = (B + BLOCK_THREADS - 1) / BLOCK_THREADS;
        SplineRow_kernel<<<g1, BLOCK_THREADS, 0, stream>>>(x, wsN, wsM, B);
        const int n4 = out_size / 4;
        SplineExpand_kernel<<<2048, BLOCK_THREADS, 0, stream>>>(
            wsN, wsM, (f32x4*)d_out, n4, out_size, B);
    } else {
        const int nblocks = (B + 127) / 128;
        SplineFused_kernel<<<nblocks, BLOCK_THREADS, 0, stream>>>(x, (float*)d_out, B);
    }
}